// Round 6
// baseline (234.684 us; speedup 1.0000x reference)
//
#include <hip/hip_runtime.h>

typedef short short8 __attribute__((ext_vector_type(8)));
typedef float f32x4 __attribute__((ext_vector_type(4)));
typedef unsigned short u16;

namespace {
constexpr int NIMG = 16;
constexpr int CIN  = 256;
constexpr int HIMG = 56;
constexpr int WIMG = 56;
constexpr int KOUT = 256;
constexpr int PIX  = HIMG * WIMG;          // 3136
constexpr int HPAD = 58;
constexpr int PP   = HPAD * HPAD;          // 3364
constexpr int TILES = 26;                  // 26*128 = 3328 >= 3246
constexpr int NX   = NIMG * CIN * PIX;     // 12,845,056
constexpr int NGX  = (NX + 35) / 36;       // 356,808
constexpr int NWEL = KOUT * CIN * 9;       // 589,824
constexpr int XQ_HALVES = NIMG * 32 * PP * 8;   // 13,778,944
constexpr int NHALO = NIMG * 32 * 228;     // 116,736
constexpr int QBLK = 1393;                 // full x-quant blocks
constexpr int XB   = QBLK + 1;             // 1394 (incl. tail block)
constexpr int WB   = 64;                   // weight-quant blocks
constexpr int HB   = (NHALO + 255) / 256;  // 456 halo blocks
}

// ---------------------------------------------------------------------------
// Fused quant kernel, dispatched by block range:
//   [0, XB)          : BFP quantize x (NCHW fp32) -> NCHW bf16, LDS-staged
//   [XB, XB+WB)      : BFP quantize weights -> wt4[cs][rs][fkk][kout][8]
//   [XB+WB, ...)     : zero halo ring of xq2 (chunked padded layout)
// ---------------------------------------------------------------------------
__global__ __launch_bounds__(256) void quant_fused(
        const float* __restrict__ x, u16* __restrict__ qn,
        const float* __restrict__ wsrc, u16* __restrict__ wt4,
        u16* __restrict__ xq2) {
    __shared__ float sf[9216];                 // 36 KB staging (x path only)
    const int b = blockIdx.x;
    const int t = threadIdx.x;

    if (b < QBLK) {
        u16* su = (u16*)sf;
        const size_t base = (size_t)b * 9216;
        const float4* src = (const float4*)(x + base);
#pragma unroll
        for (int j = 0; j < 9; j++)
            *(float4*)&sf[4 * (t + 256 * j)] = src[t + 256 * j];
        __syncthreads();
        float v[36];
#pragma unroll
        for (int j = 0; j < 36; j++) v[j] = sf[36 * t + j];
        float ma = 0.f;
#pragma unroll
        for (int j = 0; j < 36; j++) ma = fmaxf(ma, fabsf(v[j]));
        float scale = 0.f, rinv = 0.f;
        if (ma != 0.f) {
            float e = floorf(log2f(ma));
            scale = exp2f(e - 7.f);
            rinv  = exp2f(7.f - e);
        }
        u16 qq[36];
#pragma unroll
        for (int j = 0; j < 36; j++) {
            float q = rintf(v[j] * rinv);                 // round-half-even
            q = fminf(fmaxf(q, -128.f), 127.f) * scale;
            qq[j] = (u16)(__float_as_uint(q) >> 16);      // exact bf16
        }
        __syncthreads();
#pragma unroll
        for (int j = 0; j < 36; j++) su[36 * t + j] = qq[j];
        __syncthreads();
        uint2* dst = (uint2*)(qn + base);
        const uint2* s2 = (const uint2*)su;
#pragma unroll
        for (int j = 0; j < 9; j++) dst[t + 256 * j] = s2[t + 256 * j];
    } else if (b == QBLK) {
        int g = b * 256 + t;
        if (g >= NGX) return;
        int gb = g * 36;
        int cnt = NX - gb; if (cnt > 36) cnt = 36;
        float v[36];
        for (int j = 0; j < 36; j++) v[j] = (j < cnt) ? x[gb + j] : 0.f;
        float ma = 0.f;
        for (int j = 0; j < 36; j++) ma = fmaxf(ma, fabsf(v[j]));
        float scale = 0.f, rinv = 0.f;
        if (ma != 0.f) {
            float e = floorf(log2f(ma));
            scale = exp2f(e - 7.f);
            rinv  = exp2f(7.f - e);
        }
        for (int j = 0; j < cnt; j++) {
            float q = rintf(v[j] * rinv);
            q = fminf(fmaxf(q, -128.f), 127.f) * scale;
            qn[gb + j] = (u16)(__float_as_uint(q) >> 16);
        }
    } else if (b < XB + WB) {
        int g = (b - XB) * 256 + t;               // < 16384
        int base = g * 36;
        float v[36];
        const float4* p4 = (const float4*)(wsrc + base);
#pragma unroll
        for (int j = 0; j < 9; j++) {
            float4 tt = p4[j];
            v[4*j+0] = tt.x; v[4*j+1] = tt.y; v[4*j+2] = tt.z; v[4*j+3] = tt.w;
        }
        float ma = 0.f;
#pragma unroll
        for (int j = 0; j < 36; j++) ma = fmaxf(ma, fabsf(v[j]));
        float scale = 0.f, rinv = 0.f;
        if (ma != 0.f) {
            float e = floorf(log2f(ma));
            scale = exp2f(e - 7.f);
            rinv  = exp2f(7.f - e);
        }
        int k  = g >> 6;
        int c0 = (g & 63) * 4;
#pragma unroll
        for (int j = 0; j < 36; j++) {
            float q = rintf(v[j] * rinv);
            q = fminf(fmaxf(q, -128.f), 127.f) * scale;
            int c  = c0 + j / 9;
            int rs = j % 9;
            // wt4[cs=c>>5][rs][fkk=(c>>3)&3][k][c&7]
            int idx = (((((c >> 5) * 9 + rs) * 4 + ((c >> 3) & 3)) * KOUT) + k) * 8 + (c & 7);
            wt4[idx] = (u16)(__float_as_uint(q) >> 16);
        }
    } else {
        int tt = (b - XB - WB) * 256 + t;
        if (tt >= NHALO) return;
        int s   = tt % 228;
        int ccn = tt / 228;
        int cc = ccn & 31, n = ccn >> 5;
        int ph, pw;
        if (s < 58)       { ph = 0;  pw = s; }
        else if (s < 116) { ph = 57; pw = s - 58; }
        else { int r = s - 116; ph = 1 + (r >> 1); pw = (r & 1) * 57; }
        *(uint4*)(xq2 + ((size_t)(n * 32 + cc) * PP + ph * HPAD + pw) * 8) =
            make_uint4(0, 0, 0, 0);
    }
}

// ---------------------------------------------------------------------------
// LDS-tiled scatter NCHW bf16 -> channel-chunked padded layout
//   xq2[n][cc=c/8][pp=ph*58+pw][8], interior only.
// ---------------------------------------------------------------------------
__global__ __launch_bounds__(256) void transpose_x(
        const u16* __restrict__ qn, u16* __restrict__ xq2) {
    __shared__ uint tile[64][65];
    const int t  = threadIdx.x;
    const int p0 = blockIdx.x * 64;
    const int c0 = blockIdx.y * 64;
    const int n  = blockIdx.z;

    const int jc  = t & 7;
    const int ci0 = t >> 3;
#pragma unroll
    for (int l = 0; l < 2; l++) {
        int ci = ci0 + 32 * l;
        const short8 vv = *(const short8*)(qn + (size_t)n * CIN * PIX
                                           + (c0 + ci) * PIX + p0 + jc * 8);
#pragma unroll
        for (int j = 0; j < 8; j++)
            tile[ci][jc * 8 + j] = (uint)(u16)vv[j];
    }
    __syncthreads();

    const int pi  = t & 63;
    const int cc0 = t >> 6;
    const int p = p0 + pi;
    const int i = p / WIMG, j = p % WIMG;
    const int pp = (i + 1) * HPAD + (j + 1);
#pragma unroll
    for (int s = 0; s < 2; s++) {
        int cc = cc0 + 4 * s;
        short8 o;
#pragma unroll
        for (int q = 0; q < 8; q++)
            o[q] = (short)tile[cc * 8 + q][pi];
        *(short8*)(xq2 + ((size_t)(n * 32 + (c0 >> 3) + cc) * PP + pp) * 8) = o;
    }
}

// ---------------------------------------------------------------------------
// Implicit-GEMM conv, BARRIER-FREE: both MFMA fragments loaded directly from
// global (L2-hot) as 16B dwordx4 per lane — no LDS, no __syncthreads in the
// K-loop. 72 stages = 8 cs (dynamic loop) x 9 taps (unrolled); compiler
// pipelines loads across MFMAs with fine-grained vmcnt.
//   A-frag lane value: W[row=k0+wrow+frow+16i][c=cs*32+fkk*8+j]
//     = wt4[((cs*9+rs)*4+fkk)*256 + row][j]   (4x256B chunks per wave-load)
//   B-frag lane value: X[c][pix=t0+wcol+frow+16j]
//     = xq2[(n*32+cs*4+fkk)*PP + pix + xoff][j]
// Geometry identical to the R3-verified LDS mapping.
// ---------------------------------------------------------------------------
__global__ __launch_bounds__(256) void conv_kernel(
        const u16* __restrict__ xq2, const u16* __restrict__ wt4,
        const float* __restrict__ bias, float* __restrict__ out) {
    const int tid  = threadIdx.x;
    const int lane = tid & 63;
    const int wv   = tid >> 6;
    const int bx   = blockIdx.x;
    const int n    = bx / TILES;
    const int t0   = (bx % TILES) * 128;
    const int k0   = blockIdx.y * 128;

    const int frow = lane & 15;
    const int fkk  = lane >> 4;

    // half-index bases (all further offsets are compile-time constants)
    const u16* Ab = wt4 + fkk * 2048 + (k0 + (wv >> 1) * 64 + frow) * 8;
    const u16* Bb = xq2 + ((n * 32 + fkk) * PP + t0 + (wv & 1) * 64 + frow) * 8;

    f32x4 acc[4][4] = {};

    for (int cs = 0; cs < 8; cs++) {
        const u16* Acs = Ab + cs * 73728;        // cs stride: 9*4*256*8
        const u16* Bcs = Bb + cs * 107648;       // cs stride: 4*PP*8
#pragma unroll
        for (int rs = 0; rs < 9; rs++) {
            const int xoff8 = ((rs / 3) * HPAD + (rs % 3)) * 8;
            short8 af[4], bf[4];
#pragma unroll
            for (int i = 0; i < 4; i++)
                af[i] = *(const short8*)(Acs + rs * 8192 + i * 128);
#pragma unroll
            for (int j = 0; j < 4; j++)
                bf[j] = *(const short8*)(Bcs + xoff8 + j * 128);
#pragma unroll
            for (int i = 0; i < 4; i++)
#pragma unroll
                for (int j = 0; j < 4; j++)
                    acc[i][j] = __builtin_amdgcn_mfma_f32_16x16x32_bf16(
                        af[i], bf[j], acc[i][j], 0, 0, 0);
        }
    }

    // epilogue: rows = outch, cols = padded pixel t0+col; skip invalid cols
    const int kbase = k0 + (wv >> 1) * 64 + fkk * 4;
    const int mbase = (wv & 1) * 64 + frow;
#pragma unroll
    for (int j = 0; j < 4; j++) {
        int ppp = t0 + mbase + j * 16;
        int h = ppp / HPAD, w = ppp % HPAD;
        if (w < WIMG && h < HIMG) {
            float* ob = out + (size_t)n * KOUT * PIX + h * WIMG + w;
#pragma unroll
            for (int i = 0; i < 4; i++) {
                int kch = kbase + i * 16;
#pragma unroll
                for (int r = 0; r < 4; r++)
                    ob[(size_t)(kch + r) * PIX] = acc[i][j][r] + bias[kch + r];
            }
        }
    }
}

// ---------------------------------------------------------------------------
extern "C" void kernel_launch(void* const* d_in, const int* in_sizes, int n_in,
                              void* d_out, int out_size, void* d_ws, size_t ws_size,
                              hipStream_t stream) {
    const float* x   = (const float*)d_in[0];
    const float* wgt = (const float*)d_in[1];
    const float* bs  = (const float*)d_in[2];
    float* out = (float*)d_out;

    u16* xq2 = (u16*)d_ws;                 // 27.56 MB chunked padded activations
    u16* wt4 = xq2 + XQ_HALVES;            // 1.18 MB  fragment-layout weights
    u16* qn  = wt4 + NWEL;                 // 25.69 MB NCHW bf16 intermediate

    quant_fused<<<XB + WB + HB, 256, 0, stream>>>(x, qn, wgt, wt4, xq2);
    transpose_x<<<dim3(PIX / 64, CIN / 64, NIMG), 256, 0, stream>>>(qn, xq2);
    conv_kernel<<<dim3(NIMG * TILES, 2), 256, 0, stream>>>(xq2, wt4, bs, out);
}